// Round 3
// baseline (623.000 us; speedup 1.0000x reference)
//
#include <hip/hip_runtime.h>

#define B_ 8
#define N_ 4096
#define K_ 16
#define C_ 64
#define NK_ (N_*K_)            // 65536
#define M_ (B_*N_*K_)          // 524288
#define BN_EPS_ 0.001f
#define CH_ 16                 // knn candidate chunks
#define CS_ (N_/CH_)           // 256 candidates per chunk
#define Q_ (B_*N_)             // 32768 queries
#define NB1_ (M_/128)          // 4096 blocks in layer/stats kernels

typedef short bf16x8 __attribute__((ext_vector_type(8)));   // 8 bf16 = 4 VGPRs
typedef float f32x4 __attribute__((ext_vector_type(4)));

// bf16 round-to-nearest-even (no NaN inputs in this pipeline)
static __device__ __forceinline__ unsigned short f2bf(float x) {
  unsigned u = __float_as_uint(x);
  unsigned r = (u + 0x7FFFu + ((u >> 16) & 1u)) >> 16;
  return (unsigned short)r;
}
static __device__ __forceinline__ unsigned pk2bf(float a, float b) {
  return (unsigned)f2bf(a) | ((unsigned)f2bf(b) << 16);
}

// ---------------- pack points (B,3,N) -> float4 (B*N) ----------------
__global__ __launch_bounds__(256) void pack_pts(const float* __restrict__ p,
                                                float4* __restrict__ pf4) {
  int i = blockIdx.x * 256 + threadIdx.x;
  int b = i >> 12;
  int n = i & (N_ - 1);
  const float* base = p + (size_t)b * 3 * N_;
  pf4[i] = make_float4(base[n], base[N_ + n], base[2 * N_ + n], 0.f);
}

// ---------------- W (128x128 fp32) -> bf16 same layout ----------------
__global__ __launch_bounds__(256) void wcvt(const float* __restrict__ W,
                                            unsigned short* __restrict__ Wb) {
  int i = blockIdx.x * 256 + threadIdx.x;   // 16384
  Wb[i] = f2bf(W[i]);
}

// ---------------- w0at[d][o] = W0[o][d], d<3 ----------------
__global__ void make_w0at(const float* __restrict__ W0, float* __restrict__ w0at) {
  int o = threadIdx.x;  // 128
  for (int d = 0; d < 3; ++d) w0at[d * 128 + o] = W0[o * 131 + d];
}

// ================= KNN, candidate-split 16 ways =================
__global__ __launch_bounds__(64) void knn_part(const float4* __restrict__ p1f4,
                                               const float4* __restrict__ p2f4,
                                               float* __restrict__ pvals) {
  int lane = threadIdx.x;
  int blk = blockIdx.x;            // chunk fastest: b(8) x grp(64) x chunk(16)
  int chunk = blk & (CH_ - 1);
  int grp = (blk >> 4) & 63;
  int b = blk >> 10;
  int n1 = (grp << 6) + lane;
  int q = (b << 12) + n1;
  float4 qv = p1f4[q];
  float ax = qv.x, ay = qv.y, az = qv.z;
  const float4* pb = p2f4 + ((size_t)b << 12) + chunk * CS_;

  float s[16];
  #pragma unroll
  for (int i = 0; i < 16; ++i) s[i] = 3.0e38f;   // desc sorted; s[0]=16th smallest

  #pragma unroll 8
  for (int t = 0; t < CS_; ++t) {
    float4 c = pb[t];              // wave-uniform -> scalar load
    float dx = ax - c.x, dy = ay - c.y, dz = az - c.z;
    float d = __fadd_rn(__fadd_rn(__fmul_rn(dx, dx), __fmul_rn(dy, dy)), __fmul_rn(dz, dz));
    #pragma unroll
    for (int i = 0; i < 15; ++i) s[i] = __builtin_amdgcn_fmed3f(s[i], s[i + 1], d);
    s[15] = fminf(s[15], d);
  }
  #pragma unroll
  for (int i = 0; i < 16; ++i) pvals[(size_t)(chunk * 16 + i) * Q_ + q] = s[i];
}

__global__ __launch_bounds__(256) void knn_merge(const float* __restrict__ pvals,
                                                 float* __restrict__ Tarr) {
  int q = blockIdx.x * 256 + threadIdx.x;
  float s[16];
  #pragma unroll
  for (int i = 0; i < 16; ++i) s[i] = 3.0e38f;
  #pragma unroll 8
  for (int t = 0; t < CH_ * 16; ++t) {
    float d = pvals[(size_t)t * Q_ + q];
    #pragma unroll
    for (int i = 0; i < 15; ++i) s[i] = __builtin_amdgcn_fmed3f(s[i], s[i + 1], d);
    s[15] = fminf(s[15], d);
  }
  Tarr[q] = s[0];
}

__global__ __launch_bounds__(64) void knn_cand(const float4* __restrict__ p1f4,
                                               const float4* __restrict__ p2f4,
                                               const float* __restrict__ Tarr,
                                               int* __restrict__ cidx,
                                               int* __restrict__ ccnt) {
  int lane = threadIdx.x;
  int blk = blockIdx.x;
  int chunk = blk & (CH_ - 1);
  int grp = (blk >> 4) & 63;
  int b = blk >> 10;
  int n1 = (grp << 6) + lane;
  int q = (b << 12) + n1;
  float4 qq = p1f4[q];
  float ax = qq.x, ay = qq.y, az = qq.z;
  const float4* pb = p2f4 + ((size_t)b << 12) + chunk * CS_;
  float T = Tarr[q];
  int cnt = 0;
  int base = (q * CH_ + chunk) * 16;
  #pragma unroll 4
  for (int t = 0; t < CS_; ++t) {
    float4 c = pb[t];
    float dx = ax - c.x, dy = ay - c.y, dz = az - c.z;
    float d = __fadd_rn(__fadd_rn(__fmul_rn(dx, dx), __fmul_rn(dy, dy)), __fmul_rn(dz, dz));
    if (d <= T && cnt < 16) { cidx[base + cnt] = chunk * CS_ + t; ++cnt; }
  }
  ccnt[q * CH_ + chunk] = cnt;
}

__global__ __launch_bounds__(256) void knn_combine(const int* __restrict__ cidx,
                                                   const int* __restrict__ ccnt,
                                                   int* __restrict__ idxout) {
  int q = blockIdx.x * 256 + threadIdx.x;
  int tot = 0;
  int ob = q * 16;
  for (int c = 0; c < CH_; ++c) {
    int m = ccnt[q * CH_ + c];
    const int* src = cidx + (size_t)(q * CH_ + c) * 16;
    for (int i = 0; i < m && tot < 16; ++i) idxout[ob + tot++] = src[i];
  }
}

// ---------------- P[bn][o] = sum_c W0[o][coff+c] * f[b][c][n] (+bias) + sgn*w0a[o].pt[bn] ----
// With sgn=-1/pts=p1: A[n,o]. With sgn=+1/pts=p2: Bv[j,o].  x0 = A[n] + Bv[j].
__global__ __launch_bounds__(256) void pkern(const float* __restrict__ f,
                                             const float* __restrict__ W0,
                                             const float* __restrict__ bias,
                                             const float4* __restrict__ pf4,
                                             const float* __restrict__ w0at,
                                             float sgn,
                                             float* __restrict__ P, int coff) {
  __shared__ float fx[32 * 65];
  __shared__ __align__(16) float Wl[64 * 132];
  int tid = threadIdx.x;
  int bn0 = blockIdx.x * 32;
  int b = bn0 >> 12, nb0 = bn0 & (N_ - 1);

  for (int u = tid; u < 32 * 64; u += 256) {
    int c = u >> 5, nl = u & 31;
    fx[nl * 65 + c] = f[((size_t)b * C_ + c) * N_ + nb0 + nl];
  }
  for (int u = tid; u < 128 * 64; u += 256) {
    int o = u >> 6, c = u & 63;
    Wl[c * 132 + o] = W0[o * 131 + coff + c];
  }
  __syncthreads();

  int og = tid & 15, np_ = tid >> 4;
  int o0 = og * 8;
  int na = np_ * 2, nb = na + 1;
  float acc0[8], acc1[8];
  #pragma unroll
  for (int j = 0; j < 8; ++j) {
    float bv = bias ? bias[o0 + j] : 0.f;
    acc0[j] = bv; acc1[j] = bv;
  }
  for (int c = 0; c < 64; ++c) {
    float x0 = fx[na * 65 + c], x1 = fx[nb * 65 + c];
    float4 wa = *(const float4*)&Wl[c * 132 + o0];
    float4 wb = *(const float4*)&Wl[c * 132 + o0 + 4];
    float w[8] = {wa.x, wa.y, wa.z, wa.w, wb.x, wb.y, wb.z, wb.w};
    #pragma unroll
    for (int j = 0; j < 8; ++j) {
      acc0[j] = fmaf(x0, w[j], acc0[j]);
      acc1[j] = fmaf(x1, w[j], acc1[j]);
    }
  }
  // fold point dot-product: P += sgn * (w0a . pt)
  float4 pa = pf4[bn0 + na], pb_ = pf4[bn0 + nb];
  #pragma unroll
  for (int j = 0; j < 8; ++j) {
    float wx = w0at[o0 + j], wy = w0at[128 + o0 + j], wz = w0at[256 + o0 + j];
    acc0[j] += sgn * (wx * pa.x + wy * pa.y + wz * pa.z);
    acc1[j] += sgn * (wx * pb_.x + wy * pb_.y + wz * pb_.z);
  }
  float* Pa = P + (size_t)(bn0 + na) * 128 + o0;
  float* Pb = P + (size_t)(bn0 + nb) * 128 + o0;
  *(float4*)Pa = make_float4(acc0[0], acc0[1], acc0[2], acc0[3]);
  *(float4*)(Pa + 4) = make_float4(acc0[4], acc0[5], acc0[6], acc0[7]);
  *(float4*)Pb = make_float4(acc1[0], acc1[1], acc1[2], acc1[3]);
  *(float4*)(Pb + 4) = make_float4(acc1[4], acc1[5], acc1[6], acc1[7]);
}

// ---------------- gather ONCE: x0b = bf16(A[n] + Bv[j]); BN0 partials on rounded values ----
__global__ __launch_bounds__(256) void gstats_kernel(
    const float* __restrict__ A, const float* __restrict__ Bv,
    const int* __restrict__ idx, unsigned short* __restrict__ x0b,
    float* __restrict__ part) {
  __shared__ float sred[4 * 128 * 2];
  int tid = threadIdx.x;
  int R0 = blockIdx.x * 128;
  int b = R0 >> 16;
  int n0 = (R0 & (NK_ - 1)) >> 4;
  int cc = (tid & 15) * 8;
  int r0l = tid >> 4;

  int jj[8];
  #pragma unroll
  for (int p = 0; p < 8; ++p) jj[p] = idx[R0 + r0l + p * 16];

  float ssum[8], ssq[8];
  #pragma unroll
  for (int u = 0; u < 8; ++u) { ssum[u] = 0.f; ssq[u] = 0.f; }

  #pragma unroll
  for (int p = 0; p < 8; ++p) {
    const float* Ar = A + (size_t)((b << 12) + n0 + p) * 128 + cc;
    const float* Br = Bv + (size_t)((b << 12) + jj[p]) * 128 + cc;
    float av[8], bv[8];
    *(float4*)&av[0] = *(const float4*)Ar;  *(float4*)&av[4] = *(const float4*)(Ar + 4);
    *(float4*)&bv[0] = *(const float4*)Br;  *(float4*)&bv[4] = *(const float4*)(Br + 4);
    unsigned short h[8];
    #pragma unroll
    for (int u = 0; u < 8; ++u) {
      float x = av[u] + bv[u];
      h[u] = f2bf(x);
      float q = __uint_as_float((unsigned)h[u] << 16);   // stats on rounded value
      ssum[u] += q;
      ssq[u] = fmaf(q, q, ssq[u]);
    }
    uint4 pk;
    pk.x = (unsigned)h[0] | ((unsigned)h[1] << 16);
    pk.y = (unsigned)h[2] | ((unsigned)h[3] << 16);
    pk.z = (unsigned)h[4] | ((unsigned)h[5] << 16);
    pk.w = (unsigned)h[6] | ((unsigned)h[7] << 16);
    *(uint4*)(x0b + (size_t)(R0 + r0l + p * 16) * 128 + cc) = pk;
  }
  int w = tid >> 6, lane = tid & 63;
  #pragma unroll
  for (int u = 0; u < 8; ++u) {
    ssum[u] += __shfl_xor(ssum[u], 16);
    ssum[u] += __shfl_xor(ssum[u], 32);
    ssq[u] += __shfl_xor(ssq[u], 16);
    ssq[u] += __shfl_xor(ssq[u], 32);
  }
  if (lane < 16) {
    #pragma unroll
    for (int u = 0; u < 8; ++u) {
      sred[(w * 128 + lane * 8 + u) * 2] = ssum[u];
      sred[(w * 128 + lane * 8 + u) * 2 + 1] = ssq[u];
    }
  }
  __syncthreads();
  if (tid < 128) {
    float a = 0.f, q2 = 0.f;
    #pragma unroll
    for (int ww = 0; ww < 4; ++ww) {
      a += sred[(ww * 128 + tid) * 2];
      q2 += sred[(ww * 128 + tid) * 2 + 1];
    }
    part[(size_t)tid * NB1_ + blockIdx.x] = a;
    part[(size_t)(128 + tid) * NB1_ + blockIdx.x] = q2;
  }
}

// ---------------- reduce partials: stats[s] = sum_i part[s][i] ----------------
__global__ __launch_bounds__(256) void reduce_stats(const float* __restrict__ part,
                                                    int nb, float* __restrict__ statso) {
  int s = blockIdx.x;     // 0..255
  int tid = threadIdx.x;
  const float* src = part + (size_t)s * nb;
  float a = 0.f;
  for (int i = tid; i < nb; i += 256) a += src[i];
  a += __shfl_xor(a, 1);  a += __shfl_xor(a, 2);  a += __shfl_xor(a, 4);
  a += __shfl_xor(a, 8);  a += __shfl_xor(a, 16); a += __shfl_xor(a, 32);
  __shared__ float red[4];
  if ((tid & 63) == 0) red[tid >> 6] = a;
  __syncthreads();
  if (tid == 0) statso[s] = red[0] + red[1] + red[2] + red[3];
}

// ---------------- BN finalize ----------------
__global__ void bnfin_kernel(const float* __restrict__ stats, const float* __restrict__ gamma,
                             const float* __restrict__ beta, float* __restrict__ bnp) {
  int o = threadIdx.x;
  const float invM = 1.0f / (float)M_;
  float mean = stats[o] * invM;
  float var = stats[128 + o] * invM - mean * mean;
  float s = gamma[o] * rsqrtf(var + BN_EPS_);
  bnp[o] = s;
  bnp[128 + o] = beta[o] - mean * s;
}

// XOR-swizzled byte address into the 128x128 bf16 LDS tile (row stride 256 B).
// Spreads the 16B column slots across banks; both writers and readers use it.
static __device__ __forceinline__ char* xsa(unsigned short* Xs, int row, int bytecol) {
  return (char*)Xs + row * 256 + (bytecol ^ ((row & 7) << 4));
}

// ---- stage: Xs = bf16(relu(fma(s0, x0b, t0))), linear reads, swizzled LDS writes ----
static __device__ __forceinline__ void stage_lin(
    unsigned short* Xs, const unsigned short* x0b, const float* bnp0,
    int R0, int tid) {
  int cc = (tid & 15) * 8;
  int r0l = tid >> 4;
  float svv[8], tvv[8];
  *(float4*)&svv[0] = *(const float4*)(bnp0 + cc);       *(float4*)&svv[4] = *(const float4*)(bnp0 + cc + 4);
  *(float4*)&tvv[0] = *(const float4*)(bnp0 + 128 + cc); *(float4*)&tvv[4] = *(const float4*)(bnp0 + 132 + cc);
  #pragma unroll
  for (int p = 0; p < 8; ++p) {
    uint4 pv = *(const uint4*)(x0b + (size_t)(R0 + r0l + p * 16) * 128 + cc);
    float xv[8];
    xv[0] = __uint_as_float(pv.x << 16); xv[1] = __uint_as_float(pv.x & 0xFFFF0000u);
    xv[2] = __uint_as_float(pv.y << 16); xv[3] = __uint_as_float(pv.y & 0xFFFF0000u);
    xv[4] = __uint_as_float(pv.z << 16); xv[5] = __uint_as_float(pv.z & 0xFFFF0000u);
    xv[6] = __uint_as_float(pv.w << 16); xv[7] = __uint_as_float(pv.w & 0xFFFF0000u);
    float y[8];
    #pragma unroll
    for (int u = 0; u < 8; ++u) y[u] = fmaxf(fmaf(svv[u], xv[u], tvv[u]), 0.f);
    uint4 pk;
    pk.x = pk2bf(y[0], y[1]); pk.y = pk2bf(y[2], y[3]);
    pk.z = pk2bf(y[4], y[5]); pk.w = pk2bf(y[6], y[7]);
    *(uint4*)xsa(Xs, r0l + p * 16, 16 * (tid & 15)) = pk;
  }
}

// ---------------- pass1: linear stage -> GEMM W1 -> BN1 partials ONLY ----------------
__global__ __launch_bounds__(256) void pass1_kernel(
    const unsigned short* __restrict__ x0b, const float* __restrict__ bnp0,
    const unsigned short* __restrict__ W1b, const float* __restrict__ b1,
    float* __restrict__ part) {
  __shared__ __align__(16) unsigned short Xs[128 * 128];   // 32 KB; sred overlays after GEMM
  float* sred = (float*)Xs;
  int tid = threadIdx.x;
  int R0 = blockIdx.x * 128;

  stage_lin(Xs, x0b, bnp0, R0, tid);
  __syncthreads();

  // ---- MFMA GEMM1 ----
  int w = tid >> 6, lane = tid & 63;
  int m16 = lane & 15, qd = lane >> 4;
  int ar = w * 32 + m16;
  f32x4 acc[2][8];
  #pragma unroll
  for (int mt = 0; mt < 2; ++mt)
    #pragma unroll
    for (int nt = 0; nt < 8; ++nt) acc[mt][nt] = (f32x4){0.f, 0.f, 0.f, 0.f};

  const unsigned short* Bb = W1b + m16 * 128 + qd * 8;
  #pragma unroll 1
  for (int q = 0; q < 4; ++q) {
    int bc = 16 * qd + 64 * q;
    bf16x8 A0 = *(const bf16x8*)xsa(Xs, ar, bc);
    bf16x8 A1 = *(const bf16x8*)xsa(Xs, ar + 16, bc);
    #pragma unroll
    for (int nt = 0; nt < 8; ++nt) {
      bf16x8 Bv_ = *(const bf16x8*)(Bb + nt * 16 * 128 + q * 32);
      acc[0][nt] = __builtin_amdgcn_mfma_f32_16x16x32_bf16(A0, Bv_, acc[0][nt], 0, 0, 0);
      acc[1][nt] = __builtin_amdgcn_mfma_f32_16x16x32_bf16(A1, Bv_, acc[1][nt], 0, 0, 0);
    }
  }

  // ---- epilogue: bias + stats straight from accumulators (registers only) ----
  float ssum[8], ssq[8];
  #pragma unroll
  for (int nt = 0; nt < 8; ++nt) { ssum[nt] = 0.f; ssq[nt] = 0.f; }
  #pragma unroll
  for (int nt = 0; nt < 8; ++nt) {
    float bb = b1[nt * 16 + m16];
    #pragma unroll
    for (int mt = 0; mt < 2; ++mt) {
      #pragma unroll
      for (int rg = 0; rg < 4; ++rg) {
        float y = acc[mt][nt][rg] + bb;
        ssum[nt] += y;
        ssq[nt] = fmaf(y, y, ssq[nt]);
      }
    }
  }
  #pragma unroll
  for (int nt = 0; nt < 8; ++nt) {
    ssum[nt] += __shfl_xor(ssum[nt], 16);
    ssum[nt] += __shfl_xor(ssum[nt], 32);
    ssq[nt] += __shfl_xor(ssq[nt], 16);
    ssq[nt] += __shfl_xor(ssq[nt], 32);
  }
  __syncthreads();   // all Xs reads complete before sred overlay
  if (lane < 16) {
    #pragma unroll
    for (int nt = 0; nt < 8; ++nt) {
      sred[(w * 128 + nt * 16 + lane) * 2] = ssum[nt];
      sred[(w * 128 + nt * 16 + lane) * 2 + 1] = ssq[nt];
    }
  }
  __syncthreads();
  if (tid < 128) {
    float a = 0.f, q2 = 0.f;
    #pragma unroll
    for (int ww = 0; ww < 4; ++ww) {
      a += sred[(ww * 128 + tid) * 2];
      q2 += sred[(ww * 128 + tid) * 2 + 1];
    }
    part[(size_t)tid * NB1_ + blockIdx.x] = a;
    part[(size_t)(128 + tid) * NB1_ + blockIdx.x] = q2;
  }
}

// ---------------- pass2: linear stage -> GEMM W1 -> BN1+relu -> GEMM W2 -> max/min ----------
__global__ __launch_bounds__(256) void pass2_kernel(
    const unsigned short* __restrict__ x0b, const float* __restrict__ bnp0,
    const unsigned short* __restrict__ W1b, const float* __restrict__ b1,
    const float* __restrict__ bnp1, const unsigned short* __restrict__ W2b,
    const float* __restrict__ b2, float* __restrict__ ymaxo,
    float* __restrict__ ymino, float* __restrict__ part) {
  __shared__ __align__(16) unsigned short Xs[128 * 128];
  float* sred = (float*)Xs;
  int tid = threadIdx.x;
  int R0 = blockIdx.x * 128;
  int b = R0 >> 16;
  int n0 = (R0 & (NK_ - 1)) >> 4;

  stage_lin(Xs, x0b, bnp0, R0, tid);
  __syncthreads();

  // ---- MFMA GEMM1 ----
  int w = tid >> 6, lane = tid & 63;
  int m16 = lane & 15, qd = lane >> 4;
  int ar = w * 32 + m16;
  f32x4 acc[2][8];
  #pragma unroll
  for (int mt = 0; mt < 2; ++mt)
    #pragma unroll
    for (int nt = 0; nt < 8; ++nt) acc[mt][nt] = (f32x4){0.f, 0.f, 0.f, 0.f};

  const unsigned short* Bb = W1b + m16 * 128 + qd * 8;
  #pragma unroll 1
  for (int q = 0; q < 4; ++q) {
    int bc = 16 * qd + 64 * q;
    bf16x8 A0 = *(const bf16x8*)xsa(Xs, ar, bc);
    bf16x8 A1 = *(const bf16x8*)xsa(Xs, ar + 16, bc);
    #pragma unroll
    for (int nt = 0; nt < 8; ++nt) {
      bf16x8 Bv_ = *(const bf16x8*)(Bb + nt * 16 * 128 + q * 32);
      acc[0][nt] = __builtin_amdgcn_mfma_f32_16x16x32_bf16(A0, Bv_, acc[0][nt], 0, 0, 0);
      acc[1][nt] = __builtin_amdgcn_mfma_f32_16x16x32_bf16(A1, Bv_, acc[1][nt], 0, 0, 0);
    }
  }

  // ---- epilogue1: x1bn = relu(s1*acc + (s1*b1+t1)) -> own 32-row quarter of Xs.
  // No barrier needed: each wave reads/writes only rows [w*32, w*32+32) from here on.
  #pragma unroll
  for (int nt = 0; nt < 8; ++nt) {
    int col = nt * 16 + m16;
    float sc = bnp1[col];
    float tc = fmaf(sc, b1[col], bnp1[128 + col]);
    #pragma unroll
    for (int mt = 0; mt < 2; ++mt) {
      #pragma unroll
      for (int rg = 0; rg < 4; ++rg) {
        int row = w * 32 + mt * 16 + qd * 4 + rg;
        float y = fmaxf(fmaf(sc, acc[mt][nt][rg], tc), 0.f);
        *(unsigned short*)xsa(Xs, row, 2 * col) = f2bf(y);
      }
    }
  }

  // ---- MFMA GEMM2 ----
  #pragma unroll
  for (int mt = 0; mt < 2; ++mt)
    #pragma unroll
    for (int nt = 0; nt < 8; ++nt) acc[mt][nt] = (f32x4){0.f, 0.f, 0.f, 0.f};

  const unsigned short* Bb2 = W2b + m16 * 128 + qd * 8;
  #pragma unroll 1
  for (int q = 0; q < 4; ++q) {
    int bc = 16 * qd + 64 * q;
    bf16x8 A0 = *(const bf16x8*)xsa(Xs, ar, bc);
    bf16x8 A1 = *(const bf16x8*)xsa(Xs, ar + 16, bc);
    #pragma unroll
    for (int nt = 0; nt < 8; ++nt) {
      bf16x8 Bv_ = *(const bf16x8*)(Bb2 + nt * 16 * 128 + q * 32);
      acc[0][nt] = __builtin_amdgcn_mfma_f32_16x16x32_bf16(A0, Bv_, acc[0][nt], 0, 0, 0);
      acc[1][nt] = __builtin_amdgcn_mfma_f32_16x16x32_bf16(A1, Bv_, acc[1][nt], 0, 0, 0);
    }
  }

  // ---- epilogue2: bias, stats, k-max/min over 16 rows ----
  float ssum[8], ssq[8], mxv[2][8], mnv[2][8];
  #pragma unroll
  for (int nt = 0; nt < 8; ++nt) { ssum[nt] = 0.f; ssq[nt] = 0.f; }
  #pragma unroll
  for (int nt = 0; nt < 8; ++nt) {
    float bb = b2[nt * 16 + m16];
    #pragma unroll
    for (int mt = 0; mt < 2; ++mt) {
      float y0 = acc[mt][nt][0] + bb;
      float mx = y0, mn = y0, su = y0, sq = y0 * y0;
      #pragma unroll
      for (int rg = 1; rg < 4; ++rg) {
        float y = acc[mt][nt][rg] + bb;
        mx = fmaxf(mx, y); mn = fminf(mn, y);
        su += y; sq = fmaf(y, y, sq);
      }
      mxv[mt][nt] = mx; mnv[mt][nt] = mn;
      ssum[nt] += su; ssq[nt] += sq;
    }
  }
  #pragma unroll
  for (int nt = 0; nt < 8; ++nt)
    #pragma unroll
    for (int mt = 0; mt < 2; ++mt) {
      mxv[mt][nt] = fmaxf(mxv[mt][nt], __shfl_xor(mxv[mt][nt], 16));
      mxv[mt][nt] = fmaxf(mxv[mt][nt], __shfl_xor(mxv[mt][nt], 32));
      mnv[mt][nt] = fminf(mnv[mt][nt], __shfl_xor(mnv[mt][nt], 16));
      mnv[mt][nt] = fminf(mnv[mt][nt], __shfl_xor(mnv[mt][nt], 32));
    }
  if (lane < 16) {
    #pragma unroll
    for (int mt = 0; mt < 2; ++mt) {
      int n = n0 + w * 2 + mt;
      size_t base = ((size_t)(b << 12) + n) * 128;
      #pragma unroll
      for (int nt = 0; nt < 8; ++nt) {
        ymaxo[base + nt * 16 + lane] = mxv[mt][nt];
        ymino[base + nt * 16 + lane] = mnv[mt][nt];
      }
    }
  }
  #pragma unroll
  for (int nt = 0; nt < 8; ++nt) {
    ssum[nt] += __shfl_xor(ssum[nt], 16);
    ssum[nt] += __shfl_xor(ssum[nt], 32);
    ssq[nt] += __shfl_xor(ssq[nt], 16);
    ssq[nt] += __shfl_xor(ssq[nt], 32);
  }
  __syncthreads();   // all Xs reads (GEMM2) complete before sred overlay
  if (lane < 16) {
    #pragma unroll
    for (int nt = 0; nt < 8; ++nt) {
      sred[(w * 128 + nt * 16 + lane) * 2] = ssum[nt];
      sred[(w * 128 + nt * 16 + lane) * 2 + 1] = ssq[nt];
    }
  }
  __syncthreads();
  if (tid < 128) {
    float a = 0.f, q2 = 0.f;
    #pragma unroll
    for (int ww = 0; ww < 4; ++ww) {
      a += sred[(ww * 128 + tid) * 2];
      q2 += sred[(ww * 128 + tid) * 2 + 1];
    }
    part[(size_t)tid * NB1_ + blockIdx.x] = a;
    part[(size_t)(128 + tid) * NB1_ + blockIdx.x] = q2;
  }
}

// ---------------- final: BN2+relu on max/min, transpose to (B,128,N) ----------------
__global__ __launch_bounds__(256) void final_kernel(const float* __restrict__ ymaxo,
                                                    const float* __restrict__ ymino,
                                                    const float* __restrict__ bnp2,
                                                    float* __restrict__ out) {
  __shared__ float T[64 * 129];
  int tid = threadIdx.x;
  int b = blockIdx.x >> 6;
  int n0 = (blockIdx.x & 63) * 64;
  for (int u = tid; u < 64 * 128; u += 256) {
    int nl = u >> 7, o = u & 127;
    size_t base = ((size_t)(b << 12) + n0 + nl) * 128 + o;
    float s = bnp2[o], t = bnp2[128 + o];
    float v = fmaf(s, (s >= 0.f ? ymaxo[base] : ymino[base]), t);
    T[nl * 129 + o] = fmaxf(v, 0.f);
  }
  __syncthreads();
  for (int u = tid; u < 64 * 128; u += 256) {
    int o = u >> 6, nl = u & 63;
    out[((size_t)b * 128 + o) * N_ + n0 + nl] = T[nl * 129 + o];
  }
}

extern "C" void kernel_launch(void* const* d_in, const int* in_sizes, int n_in,
                              void* d_out, int out_size, void* d_ws, size_t ws_size,
                              hipStream_t stream) {
  (void)in_sizes; (void)n_in; (void)out_size; (void)ws_size;
  const float* points1 = (const float*)d_in[0];
  const float* points2 = (const float*)d_in[1];
  const float* features1 = (const float*)d_in[2];
  const float* features2 = (const float*)d_in[3];
  const float* W0 = (const float*)d_in[4];
  const float* b0 = (const float*)d_in[5];
  const float* g0 = (const float*)d_in[6];
  const float* be0 = (const float*)d_in[7];
  const float* W1 = (const float*)d_in[8];
  const float* b1 = (const float*)d_in[9];
  const float* g1 = (const float*)d_in[10];
  const float* be1 = (const float*)d_in[11];
  const float* W2 = (const float*)d_in[12];
  const float* b2 = (const float*)d_in[13];
  const float* g2 = (const float*)d_in[14];
  const float* be2 = (const float*)d_in[15];
  float* out = (float*)d_out;

  char* ws = (char*)d_ws;
  size_t off = 0;
  auto alloc = [&](size_t bytes) -> void* {
    void* p = ws + off;
    off += (bytes + 255) & ~(size_t)255;
    return p;
  };
  int* idx = (int*)alloc((size_t)M_ * 4);
  float4* p1f4 = (float4*)alloc((size_t)B_ * N_ * 16);
  float4* p2f4 = (float4*)alloc((size_t)B_ * N_ * 16);
  float* A = (float*)alloc((size_t)B_ * N_ * 128 * 4);      // 16 MB
  float* Bv = (float*)alloc((size_t)B_ * N_ * 128 * 4);     // 16 MB
  unsigned short* W1b = (unsigned short*)alloc(128 * 128 * 2);
  unsigned short* W2b = (unsigned short*)alloc(128 * 128 * 2);
  float* w0at = (float*)alloc(3 * 128 * 4);
  float* stats = (float*)alloc(3 * 256 * 4);
  float* bnp = (float*)alloc(3 * 256 * 4);
  float* ymaxo = (float*)alloc((size_t)B_ * N_ * 128 * 4);  // 16 MB
  float* ymino = (float*)alloc((size_t)B_ * N_ * 128 * 4);  // 16 MB
  // 128 MB region: KNN scratch during KNN, then x0b (bf16 x0) for the streamed passes.
  char* bigbuf = (char*)alloc((size_t)128 * 1024 * 1024);
  float* pvals = (float*)bigbuf;                                   // 32 MB
  int* cidx = (int*)(bigbuf + (size_t)32 * 1024 * 1024);           // 32 MB
  int* ccnt = (int*)(bigbuf + (size_t)64 * 1024 * 1024);           // 2 MB
  float* Tarr = (float*)(bigbuf + (size_t)66 * 1024 * 1024);       // 128 KB
  unsigned short* x0b = (unsigned short*)bigbuf;                   // 128 MB (after KNN)

  // stats partials aliased onto dead buffers (liveness-checked):
  //  part0 (4 MB, gstats->reduce0) on ymaxo  [ymaxo first written in pass2]
  //  part1 (4 MB, pass1->reduce1)  on ymino  [ymino first written in pass2]
  //  part2 (4 MB, pass2->reduce2)  on A      [A dead after gstats]
  float* part0 = ymaxo;
  float* part1 = ymino;
  float* part2 = A;

  pack_pts<<<B_ * N_ / 256, 256, 0, stream>>>(points1, p1f4);
  pack_pts<<<B_ * N_ / 256, 256, 0, stream>>>(points2, p2f4);
  wcvt<<<64, 256, 0, stream>>>(W1, W1b);
  wcvt<<<64, 256, 0, stream>>>(W2, W2b);
  make_w0at<<<1, 128, 0, stream>>>(W0, w0at);

  knn_part<<<B_ * 64 * CH_, 64, 0, stream>>>(p1f4, p2f4, pvals);
  knn_merge<<<Q_ / 256, 256, 0, stream>>>(pvals, Tarr);
  knn_cand<<<B_ * 64 * CH_, 64, 0, stream>>>(p1f4, p2f4, Tarr, cidx, ccnt);
  knn_combine<<<Q_ / 256, 256, 0, stream>>>(cidx, ccnt, idx);

  pkern<<<B_ * N_ / 32, 256, 0, stream>>>(features1, W0, b0, p1f4, w0at, -1.f, A, 67);
  pkern<<<B_ * N_ / 32, 256, 0, stream>>>(features2, W0, nullptr, p2f4, w0at, 1.f, Bv, 3);

  gstats_kernel<<<NB1_, 256, 0, stream>>>(A, Bv, idx, x0b, part0);
  reduce_stats<<<256, 256, 0, stream>>>(part0, NB1_, stats);
  bnfin_kernel<<<1, 128, 0, stream>>>(stats, g0, be0, bnp);

  pass1_kernel<<<NB1_, 256, 0, stream>>>(x0b, bnp, W1b, b1, part1);
  reduce_stats<<<256, 256, 0, stream>>>(part1, NB1_, stats + 256);
  bnfin_kernel<<<1, 128, 0, stream>>>(stats + 256, g1, be1, bnp + 256);

  pass2_kernel<<<NB1_, 256, 0, stream>>>(x0b, bnp, W1b, b1, bnp + 256,
                                         W2b, b2, ymaxo, ymino, part2);
  reduce_stats<<<256, 256, 0, stream>>>(part2, NB1_, stats + 512);
  bnfin_kernel<<<1, 128, 0, stream>>>(stats + 512, g2, be2, bnp + 512);

  final_kernel<<<B_ * N_ / 64, 256, 0, stream>>>(ymaxo, ymino, bnp + 512, out);
}

// Round 4
// 495.285 us; speedup vs baseline: 1.2579x; 1.2579x over previous
//
#include <hip/hip_runtime.h>
#include <hip/hip_bf16.h>

#define B_ 8
#define N_ 4096
#define K_ 16
#define C_ 64
#define NK_ (N_*K_)            // 65536
#define M_ (B_*N_*K_)          // 524288
#define BN_EPS_ 0.001f
#define CH_ 16                 // knn candidate chunks
#define CS_ (N_/CH_)           // 256 candidates per chunk
#define Q_ (B_*N_)             // 32768 queries
#define NB1_ (M_/128)          // 4096 blocks in layer/stats kernels

typedef short bf16x8 __attribute__((ext_vector_type(8)));   // 8 bf16 = 4 VGPRs
typedef float f32x4 __attribute__((ext_vector_type(4)));

// packed f32x2 -> bf16x2 (RNE) via hardware cvt
static __device__ __forceinline__ unsigned pk2bf(float a, float b) {
  union { __hip_bfloat162 h; unsigned u; } c;
  c.h = __float22bfloat162_rn(make_float2(a, b));
  return c.u;
}
static __device__ __forceinline__ unsigned short f2bf1(float x) {
  union { __hip_bfloat16 h; unsigned short u; } c;
  c.h = __float2bfloat16(x);
  return c.u;
}

// ---------------- pack points (B,3,N) -> float4 (B*N) ----------------
__global__ __launch_bounds__(256) void pack_pts(const float* __restrict__ p,
                                                float4* __restrict__ pf4) {
  int i = blockIdx.x * 256 + threadIdx.x;
  int b = i >> 12;
  int n = i & (N_ - 1);
  const float* base = p + (size_t)b * 3 * N_;
  pf4[i] = make_float4(base[n], base[N_ + n], base[2 * N_ + n], 0.f);
}

// ---------------- W (128x128 fp32) -> bf16 same layout ----------------
__global__ __launch_bounds__(256) void wcvt(const float* __restrict__ W,
                                            unsigned short* __restrict__ Wb) {
  int i = blockIdx.x * 256 + threadIdx.x;   // 16384
  Wb[i] = f2bf1(W[i]);
}

// ---------------- w0at[d][o] = W0[o][d], d<3 ----------------
__global__ void make_w0at(const float* __restrict__ W0, float* __restrict__ w0at) {
  int o = threadIdx.x;  // 128
  for (int d = 0; d < 3; ++d) w0at[d * 128 + o] = W0[o * 131 + d];
}

// ---------------- zero the 3x256 stats buffer (atomic targets) ----------------
__global__ void zero_stats(float* __restrict__ stats) {
  int i = blockIdx.x * 256 + threadIdx.x;   // 768
  stats[i] = 0.f;
}

// ================= KNN, candidate-split 16 ways =================
__global__ __launch_bounds__(64) void knn_part(const float4* __restrict__ p1f4,
                                               const float4* __restrict__ p2f4,
                                               float* __restrict__ pvals) {
  int lane = threadIdx.x;
  int blk = blockIdx.x;            // chunk fastest: b(8) x grp(64) x chunk(16)
  int chunk = blk & (CH_ - 1);
  int grp = (blk >> 4) & 63;
  int b = blk >> 10;
  int n1 = (grp << 6) + lane;
  int q = (b << 12) + n1;
  float4 qv = p1f4[q];
  float ax = qv.x, ay = qv.y, az = qv.z;
  const float4* pb = p2f4 + ((size_t)b << 12) + chunk * CS_;

  float s[16];
  #pragma unroll
  for (int i = 0; i < 16; ++i) s[i] = 3.0e38f;   // desc sorted; s[0]=16th smallest

  #pragma unroll 8
  for (int t = 0; t < CS_; ++t) {
    float4 c = pb[t];              // wave-uniform -> scalar load
    float dx = ax - c.x, dy = ay - c.y, dz = az - c.z;
    float d = __fadd_rn(__fadd_rn(__fmul_rn(dx, dx), __fmul_rn(dy, dy)), __fmul_rn(dz, dz));
    #pragma unroll
    for (int i = 0; i < 15; ++i) s[i] = __builtin_amdgcn_fmed3f(s[i], s[i + 1], d);
    s[15] = fminf(s[15], d);
  }
  #pragma unroll
  for (int i = 0; i < 16; ++i) pvals[(size_t)(chunk * 16 + i) * Q_ + q] = s[i];
}

__global__ __launch_bounds__(256) void knn_merge(const float* __restrict__ pvals,
                                                 float* __restrict__ Tarr) {
  int q = blockIdx.x * 256 + threadIdx.x;
  float s[16];
  #pragma unroll
  for (int i = 0; i < 16; ++i) s[i] = 3.0e38f;
  #pragma unroll 8
  for (int t = 0; t < CH_ * 16; ++t) {
    float d = pvals[(size_t)t * Q_ + q];
    #pragma unroll
    for (int i = 0; i < 15; ++i) s[i] = __builtin_amdgcn_fmed3f(s[i], s[i + 1], d);
    s[15] = fminf(s[15], d);
  }
  Tarr[q] = s[0];
}

__global__ __launch_bounds__(64) void knn_cand(const float4* __restrict__ p1f4,
                                               const float4* __restrict__ p2f4,
                                               const float* __restrict__ Tarr,
                                               int* __restrict__ cidx,
                                               int* __restrict__ ccnt) {
  int lane = threadIdx.x;
  int blk = blockIdx.x;
  int chunk = blk & (CH_ - 1);
  int grp = (blk >> 4) & 63;
  int b = blk >> 10;
  int n1 = (grp << 6) + lane;
  int q = (b << 12) + n1;
  float4 qq = p1f4[q];
  float ax = qq.x, ay = qq.y, az = qq.z;
  const float4* pb = p2f4 + ((size_t)b << 12) + chunk * CS_;
  float T = Tarr[q];
  int cnt = 0;
  int base = (q * CH_ + chunk) * 16;
  #pragma unroll 4
  for (int t = 0; t < CS_; ++t) {
    float4 c = pb[t];
    float dx = ax - c.x, dy = ay - c.y, dz = az - c.z;
    float d = __fadd_rn(__fadd_rn(__fmul_rn(dx, dx), __fmul_rn(dy, dy)), __fmul_rn(dz, dz));
    if (d <= T && cnt < 16) { cidx[base + cnt] = chunk * CS_ + t; ++cnt; }
  }
  ccnt[q * CH_ + chunk] = cnt;
}

__global__ __launch_bounds__(256) void knn_combine(const int* __restrict__ cidx,
                                                   const int* __restrict__ ccnt,
                                                   int* __restrict__ idxout) {
  int q = blockIdx.x * 256 + threadIdx.x;
  int tot = 0;
  int ob = q * 16;
  for (int c = 0; c < CH_; ++c) {
    int m = ccnt[q * CH_ + c];
    const int* src = cidx + (size_t)(q * CH_ + c) * 16;
    for (int i = 0; i < m && tot < 16; ++i) idxout[ob + tot++] = src[i];
  }
}

// ---------------- P[bn][o] = sum_c W0[o][coff+c] * f[b][c][n] (+bias) + sgn*w0a[o].pt[bn] ----
__global__ __launch_bounds__(256) void pkern(const float* __restrict__ f,
                                             const float* __restrict__ W0,
                                             const float* __restrict__ bias,
                                             const float4* __restrict__ pf4,
                                             const float* __restrict__ w0at,
                                             float sgn,
                                             float* __restrict__ P, int coff) {
  __shared__ float fx[32 * 65];
  __shared__ __align__(16) float Wl[64 * 132];
  int tid = threadIdx.x;
  int bn0 = blockIdx.x * 32;
  int b = bn0 >> 12, nb0 = bn0 & (N_ - 1);

  for (int u = tid; u < 32 * 64; u += 256) {
    int c = u >> 5, nl = u & 31;
    fx[nl * 65 + c] = f[((size_t)b * C_ + c) * N_ + nb0 + nl];
  }
  for (int u = tid; u < 128 * 64; u += 256) {
    int o = u >> 6, c = u & 63;
    Wl[c * 132 + o] = W0[o * 131 + coff + c];
  }
  __syncthreads();

  int og = tid & 15, np_ = tid >> 4;
  int o0 = og * 8;
  int na = np_ * 2, nb = na + 1;
  float acc0[8], acc1[8];
  #pragma unroll
  for (int j = 0; j < 8; ++j) {
    float bv = bias ? bias[o0 + j] : 0.f;
    acc0[j] = bv; acc1[j] = bv;
  }
  for (int c = 0; c < 64; ++c) {
    float x0 = fx[na * 65 + c], x1 = fx[nb * 65 + c];
    float4 wa = *(const float4*)&Wl[c * 132 + o0];
    float4 wb = *(const float4*)&Wl[c * 132 + o0 + 4];
    float w[8] = {wa.x, wa.y, wa.z, wa.w, wb.x, wb.y, wb.z, wb.w};
    #pragma unroll
    for (int j = 0; j < 8; ++j) {
      acc0[j] = fmaf(x0, w[j], acc0[j]);
      acc1[j] = fmaf(x1, w[j], acc1[j]);
    }
  }
  float4 pa = pf4[bn0 + na], pb_ = pf4[bn0 + nb];
  #pragma unroll
  for (int j = 0; j < 8; ++j) {
    float wx = w0at[o0 + j], wy = w0at[128 + o0 + j], wz = w0at[256 + o0 + j];
    acc0[j] += sgn * (wx * pa.x + wy * pa.y + wz * pa.z);
    acc1[j] += sgn * (wx * pb_.x + wy * pb_.y + wz * pb_.z);
  }
  float* Pa = P + (size_t)(bn0 + na) * 128 + o0;
  float* Pb = P + (size_t)(bn0 + nb) * 128 + o0;
  *(float4*)Pa = make_float4(acc0[0], acc0[1], acc0[2], acc0[3]);
  *(float4*)(Pa + 4) = make_float4(acc0[4], acc0[5], acc0[6], acc0[7]);
  *(float4*)Pb = make_float4(acc1[0], acc1[1], acc1[2], acc1[3]);
  *(float4*)(Pb + 4) = make_float4(acc1[4], acc1[5], acc1[6], acc1[7]);
}

// ---------------- gather ONCE: x0b = bf16(A[n] + Bv[j]); BN0 partials on rounded values ----
__global__ __launch_bounds__(256) void gstats_kernel(
    const float* __restrict__ A, const float* __restrict__ Bv,
    const int* __restrict__ idx, unsigned short* __restrict__ x0b,
    float* __restrict__ part) {
  __shared__ float sred[4 * 128 * 2];
  int tid = threadIdx.x;
  int R0 = blockIdx.x * 128;
  int b = R0 >> 16;
  int n0 = (R0 & (NK_ - 1)) >> 4;
  int cc = (tid & 15) * 8;
  int r0l = tid >> 4;

  int jj[8];
  #pragma unroll
  for (int p = 0; p < 8; ++p) jj[p] = idx[R0 + r0l + p * 16];

  float ssum[8], ssq[8];
  #pragma unroll
  for (int u = 0; u < 8; ++u) { ssum[u] = 0.f; ssq[u] = 0.f; }

  #pragma unroll
  for (int p = 0; p < 8; ++p) {
    const float* Ar = A + (size_t)((b << 12) + n0 + p) * 128 + cc;
    const float* Br = Bv + (size_t)((b << 12) + jj[p]) * 128 + cc;
    float av[8], bv[8];
    *(float4*)&av[0] = *(const float4*)Ar;  *(float4*)&av[4] = *(const float4*)(Ar + 4);
    *(float4*)&bv[0] = *(const float4*)Br;  *(float4*)&bv[4] = *(const float4*)(Br + 4);
    unsigned pw[4];
    #pragma unroll
    for (int i = 0; i < 4; ++i)
      pw[i] = pk2bf(av[2 * i] + bv[2 * i], av[2 * i + 1] + bv[2 * i + 1]);
    uint4 pk; pk.x = pw[0]; pk.y = pw[1]; pk.z = pw[2]; pk.w = pw[3];
    *(uint4*)(x0b + (size_t)(R0 + r0l + p * 16) * 128 + cc) = pk;
    #pragma unroll
    for (int i = 0; i < 4; ++i) {
      float q0 = __uint_as_float(pw[i] << 16);
      float q1 = __uint_as_float(pw[i] & 0xFFFF0000u);
      ssum[2 * i] += q0;     ssq[2 * i] = fmaf(q0, q0, ssq[2 * i]);
      ssum[2 * i + 1] += q1; ssq[2 * i + 1] = fmaf(q1, q1, ssq[2 * i + 1]);
    }
  }
  int w = tid >> 6, lane = tid & 63;
  #pragma unroll
  for (int u = 0; u < 8; ++u) {
    ssum[u] += __shfl_xor(ssum[u], 16);
    ssum[u] += __shfl_xor(ssum[u], 32);
    ssq[u] += __shfl_xor(ssq[u], 16);
    ssq[u] += __shfl_xor(ssq[u], 32);
  }
  if (lane < 16) {
    #pragma unroll
    for (int u = 0; u < 8; ++u) {
      sred[(w * 128 + lane * 8 + u) * 2] = ssum[u];
      sred[(w * 128 + lane * 8 + u) * 2 + 1] = ssq[u];
    }
  }
  __syncthreads();
  if (tid < 128) {
    float a = 0.f, q2 = 0.f;
    #pragma unroll
    for (int ww = 0; ww < 4; ++ww) {
      a += sred[(ww * 128 + tid) * 2];
      q2 += sred[(ww * 128 + tid) * 2 + 1];
    }
    part[(size_t)blockIdx.x * 256 + tid] = a;
    part[(size_t)blockIdx.x * 256 + 128 + tid] = q2;
  }
}

// ---------------- reduce partials: coalesced rows + atomic finish ----------------
// part layout: [NB1_][256]. grid = NB1_/16 blocks of 256 threads.
__global__ __launch_bounds__(256) void reduce_atomic(const float* __restrict__ part,
                                                     float* __restrict__ statso) {
  int tid = threadIdx.x;
  int r0 = blockIdx.x * 16;
  float a = 0.f;
  #pragma unroll
  for (int i = 0; i < 16; ++i) a += part[(size_t)(r0 + i) * 256 + tid];
  atomicAdd(statso + tid, a);
}

// ---------------- BN finalize ----------------
__global__ void bnfin_kernel(const float* __restrict__ stats, const float* __restrict__ gamma,
                             const float* __restrict__ beta, float* __restrict__ bnp) {
  int o = threadIdx.x;
  const float invM = 1.0f / (float)M_;
  float mean = stats[o] * invM;
  float var = stats[128 + o] * invM - mean * mean;
  float s = gamma[o] * rsqrtf(var + BN_EPS_);
  bnp[o] = s;
  bnp[128 + o] = beta[o] - mean * s;
}

// XOR-swizzled byte address into the 128x128 bf16 LDS tile (row stride 256 B).
static __device__ __forceinline__ char* xsa(unsigned short* Xs, int row, int bytecol) {
  return (char*)Xs + row * 256 + (bytecol ^ ((row & 7) << 4));
}

// ---- stage: Xs = bf16(relu(fma(s0, x0b, t0))), linear reads, swizzled LDS writes ----
static __device__ __forceinline__ void stage_lin(
    unsigned short* Xs, const unsigned short* x0b, const float* bnp0,
    int R0, int tid) {
  int cc = (tid & 15) * 8;
  int r0l = tid >> 4;
  float svv[8], tvv[8];
  *(float4*)&svv[0] = *(const float4*)(bnp0 + cc);       *(float4*)&svv[4] = *(const float4*)(bnp0 + cc + 4);
  *(float4*)&tvv[0] = *(const float4*)(bnp0 + 128 + cc); *(float4*)&tvv[4] = *(const float4*)(bnp0 + 132 + cc);
  #pragma unroll
  for (int p = 0; p < 8; ++p) {
    uint4 pv = *(const uint4*)(x0b + (size_t)(R0 + r0l + p * 16) * 128 + cc);
    float xv[8];
    xv[0] = __uint_as_float(pv.x << 16); xv[1] = __uint_as_float(pv.x & 0xFFFF0000u);
    xv[2] = __uint_as_float(pv.y << 16); xv[3] = __uint_as_float(pv.y & 0xFFFF0000u);
    xv[4] = __uint_as_float(pv.z << 16); xv[5] = __uint_as_float(pv.z & 0xFFFF0000u);
    xv[6] = __uint_as_float(pv.w << 16); xv[7] = __uint_as_float(pv.w & 0xFFFF0000u);
    float y[8];
    #pragma unroll
    for (int u = 0; u < 8; ++u) y[u] = fmaxf(fmaf(svv[u], xv[u], tvv[u]), 0.f);
    uint4 pk;
    pk.x = pk2bf(y[0], y[1]); pk.y = pk2bf(y[2], y[3]);
    pk.z = pk2bf(y[4], y[5]); pk.w = pk2bf(y[6], y[7]);
    *(uint4*)xsa(Xs, r0l + p * 16, 16 * (tid & 15)) = pk;
  }
}

// ---------------- pass1: stage -> GEMM W1 (W in regs, col-split waves) -> BN1 partials ----
__global__ __launch_bounds__(256) void pass1_kernel(
    const unsigned short* __restrict__ x0b, const float* __restrict__ bnp0,
    const unsigned short* __restrict__ W1b, const float* __restrict__ b1,
    float* __restrict__ part) {
  __shared__ __align__(16) unsigned short Xs[128 * 128];   // 32 KB
  int tid = threadIdx.x;
  int R0 = blockIdx.x * 128;

  stage_lin(Xs, x0b, bnp0, R0, tid);

  int w = tid >> 6, lane = tid & 63;
  int m16 = lane & 15, qd = lane >> 4;

  // per-wave W1 slice: cols [w*32, w*32+32), 8 fragments = 32 VGPR, loaded once
  bf16x8 bf[2][4];
  #pragma unroll
  for (int nt = 0; nt < 2; ++nt) {
    const unsigned short* wb = W1b + (size_t)(w * 32 + nt * 16 + m16) * 128 + qd * 8;
    #pragma unroll
    for (int q = 0; q < 4; ++q) bf[nt][q] = *(const bf16x8*)(wb + q * 32);
  }
  __syncthreads();

  f32x4 acc[8][2];
  #pragma unroll
  for (int m = 0; m < 8; ++m) {
    acc[m][0] = (f32x4){0.f, 0.f, 0.f, 0.f};
    acc[m][1] = (f32x4){0.f, 0.f, 0.f, 0.f};
  }
  #pragma unroll
  for (int m = 0; m < 8; ++m) {
    bf16x8 a[4];
    #pragma unroll
    for (int q = 0; q < 4; ++q) a[q] = *(const bf16x8*)xsa(Xs, m * 16 + m16, 16 * qd + 64 * q);
    #pragma unroll
    for (int q = 0; q < 4; ++q) {
      acc[m][0] = __builtin_amdgcn_mfma_f32_16x16x32_bf16(a[q], bf[0][q], acc[m][0], 0, 0, 0);
      acc[m][1] = __builtin_amdgcn_mfma_f32_16x16x32_bf16(a[q], bf[1][q], acc[m][1], 0, 0, 0);
    }
  }

  // epilogue: per-col stats, wave-local (cols w*32..w*32+31)
  float ssum[2] = {0.f, 0.f}, ssq[2] = {0.f, 0.f};
  #pragma unroll
  for (int nt = 0; nt < 2; ++nt) {
    float bb = b1[w * 32 + nt * 16 + m16];
    #pragma unroll
    for (int m = 0; m < 8; ++m)
      #pragma unroll
      for (int rg = 0; rg < 4; ++rg) {
        float y = acc[m][nt][rg] + bb;
        ssum[nt] += y;
        ssq[nt] = fmaf(y, y, ssq[nt]);
      }
  }
  #pragma unroll
  for (int nt = 0; nt < 2; ++nt) {
    ssum[nt] += __shfl_xor(ssum[nt], 16);
    ssum[nt] += __shfl_xor(ssum[nt], 32);
    ssq[nt] += __shfl_xor(ssq[nt], 16);
    ssq[nt] += __shfl_xor(ssq[nt], 32);
  }
  if (lane < 16) {
    size_t pb = (size_t)blockIdx.x * 256 + w * 32;
    #pragma unroll
    for (int nt = 0; nt < 2; ++nt) {
      part[pb + nt * 16 + lane] = ssum[nt];
      part[pb + 128 + nt * 16 + lane] = ssq[nt];
    }
  }
}

// ---------------- pass2: stage -> GEMM W1 -> BN1+relu -> GEMM W2 -> max/min + partials ----
__global__ __launch_bounds__(256) void pass2_kernel(
    const unsigned short* __restrict__ x0b, const float* __restrict__ bnp0,
    const unsigned short* __restrict__ W1b, const float* __restrict__ b1,
    const float* __restrict__ bnp1, const unsigned short* __restrict__ W2b,
    const float* __restrict__ b2, float* __restrict__ ymaxo,
    float* __restrict__ ymino, float* __restrict__ part) {
  __shared__ __align__(16) unsigned short Xs[128 * 128];
  int tid = threadIdx.x;
  int R0 = blockIdx.x * 128;
  int b = R0 >> 16;
  int n0 = (R0 & (NK_ - 1)) >> 4;

  stage_lin(Xs, x0b, bnp0, R0, tid);

  int w = tid >> 6, lane = tid & 63;
  int m16 = lane & 15, qd = lane >> 4;

  bf16x8 bf[2][4];
  #pragma unroll
  for (int nt = 0; nt < 2; ++nt) {
    const unsigned short* wb = W1b + (size_t)(w * 32 + nt * 16 + m16) * 128 + qd * 8;
    #pragma unroll
    for (int q = 0; q < 4; ++q) bf[nt][q] = *(const bf16x8*)(wb + q * 32);
  }
  __syncthreads();

  f32x4 acc[8][2];
  #pragma unroll
  for (int m = 0; m < 8; ++m) {
    acc[m][0] = (f32x4){0.f, 0.f, 0.f, 0.f};
    acc[m][1] = (f32x4){0.f, 0.f, 0.f, 0.f};
  }
  #pragma unroll
  for (int m = 0; m < 8; ++m) {
    bf16x8 a[4];
    #pragma unroll
    for (int q = 0; q < 4; ++q) a[q] = *(const bf16x8*)xsa(Xs, m * 16 + m16, 16 * qd + 64 * q);
    #pragma unroll
    for (int q = 0; q < 4; ++q) {
      acc[m][0] = __builtin_amdgcn_mfma_f32_16x16x32_bf16(a[q], bf[0][q], acc[m][0], 0, 0, 0);
      acc[m][1] = __builtin_amdgcn_mfma_f32_16x16x32_bf16(a[q], bf[1][q], acc[m][1], 0, 0, 0);
    }
  }
  __syncthreads();   // all GEMM1 reads of Xs complete

  // epilogue1: X1 = relu(s1*acc + (s1*b1+t1)) -> Xs in-place (D-layout scatter)
  #pragma unroll
  for (int nt = 0; nt < 2; ++nt) {
    int col = w * 32 + nt * 16 + m16;
    float sc = bnp1[col];
    float tc = fmaf(sc, b1[col], bnp1[128 + col]);
    #pragma unroll
    for (int m = 0; m < 8; ++m)
      #pragma unroll
      for (int rg = 0; rg < 4; ++rg) {
        int row = m * 16 + qd * 4 + rg;
        float y = fmaxf(fmaf(sc, acc[m][nt][rg], tc), 0.f);
        *(unsigned short*)xsa(Xs, row, 2 * col) = f2bf1(y);
      }
  }

  // load W2 slice while waiting
  bf16x8 bf2[2][4];
  #pragma unroll
  for (int nt = 0; nt < 2; ++nt) {
    const unsigned short* wb = W2b + (size_t)(w * 32 + nt * 16 + m16) * 128 + qd * 8;
    #pragma unroll
    for (int q = 0; q < 4; ++q) bf2[nt][q] = *(const bf16x8*)(wb + q * 32);
  }
  __syncthreads();   // X1 fully written

  #pragma unroll
  for (int m = 0; m < 8; ++m) {
    acc[m][0] = (f32x4){0.f, 0.f, 0.f, 0.f};
    acc[m][1] = (f32x4){0.f, 0.f, 0.f, 0.f};
  }
  #pragma unroll
  for (int m = 0; m < 8; ++m) {
    bf16x8 a[4];
    #pragma unroll
    for (int q = 0; q < 4; ++q) a[q] = *(const bf16x8*)xsa(Xs, m * 16 + m16, 16 * qd + 64 * q);
    #pragma unroll
    for (int q = 0; q < 4; ++q) {
      acc[m][0] = __builtin_amdgcn_mfma_f32_16x16x32_bf16(a[q], bf2[0][q], acc[m][0], 0, 0, 0);
      acc[m][1] = __builtin_amdgcn_mfma_f32_16x16x32_bf16(a[q], bf2[1][q], acc[m][1], 0, 0, 0);
    }
  }

  // epilogue2: bias, k-max/min per n (= m-tile), BN2 partials
  float ssum[2] = {0.f, 0.f}, ssq[2] = {0.f, 0.f};
  #pragma unroll
  for (int nt = 0; nt < 2; ++nt) {
    float bb = b2[w * 32 + nt * 16 + m16];
    #pragma unroll
    for (int m = 0; m < 8; ++m) {
      float y0 = acc[m][nt][0] + bb;
      float mx = y0, mn = y0, su = y0, sq = y0 * y0;
      #pragma unroll
      for (int rg = 1; rg < 4; ++rg) {
        float y = acc[m][nt][rg] + bb;
        mx = fmaxf(mx, y); mn = fminf(mn, y);
        su += y; sq = fmaf(y, y, sq);
      }
      mx = fmaxf(mx, __shfl_xor(mx, 16)); mx = fmaxf(mx, __shfl_xor(mx, 32));
      mn = fminf(mn, __shfl_xor(mn, 16)); mn = fminf(mn, __shfl_xor(mn, 32));
      ssum[nt] += su; ssq[nt] += sq;
      if (lane < 16) {
        int n = n0 + m;
        size_t basey = ((size_t)(b << 12) + n) * 128 + w * 32 + nt * 16 + lane;
        ymaxo[basey] = mx;
        ymino[basey] = mn;
      }
    }
  }
  #pragma unroll
  for (int nt = 0; nt < 2; ++nt) {
    ssum[nt] += __shfl_xor(ssum[nt], 16);
    ssum[nt] += __shfl_xor(ssum[nt], 32);
    ssq[nt] += __shfl_xor(ssq[nt], 16);
    ssq[nt] += __shfl_xor(ssq[nt], 32);
  }
  if (lane < 16) {
    size_t pb = (size_t)blockIdx.x * 256 + w * 32;
    #pragma unroll
    for (int nt = 0; nt < 2; ++nt) {
      part[pb + nt * 16 + lane] = ssum[nt];
      part[pb + 128 + nt * 16 + lane] = ssq[nt];
    }
  }
}

// ---------------- final: BN2+relu on max/min, transpose to (B,128,N) ----------------
__global__ __launch_bounds__(256) void final_kernel(const float* __restrict__ ymaxo,
                                                    const float* __restrict__ ymino,
                                                    const float* __restrict__ bnp2,
                                                    float* __restrict__ out) {
  __shared__ float T[64 * 129];
  int tid = threadIdx.x;
  int b = blockIdx.x >> 6;
  int n0 = (blockIdx.x & 63) * 64;
  for (int u = tid; u < 64 * 128; u += 256) {
    int nl = u >> 7, o = u & 127;
    size_t base = ((size_t)(b << 12) + n0 + nl) * 128 + o;
    float s = bnp2[o], t = bnp2[128 + o];
    float v = fmaf(s, (s >= 0.f ? ymaxo[base] : ymino[base]), t);
    T[nl * 129 + o] = fmaxf(v, 0.f);
  }
  __syncthreads();
  for (int u = tid; u < 64 * 128; u += 256) {
    int o = u >> 6, nl = u & 63;
    out[((size_t)b * 128 + o) * N_ + n0 + nl] = T[nl * 129 + o];
  }
}

extern "C" void kernel_launch(void* const* d_in, const int* in_sizes, int n_in,
                              void* d_out, int out_size, void* d_ws, size_t ws_size,
                              hipStream_t stream) {
  (void)in_sizes; (void)n_in; (void)out_size; (void)ws_size;
  const float* points1 = (const float*)d_in[0];
  const float* points2 = (const float*)d_in[1];
  const float* features1 = (const float*)d_in[2];
  const float* features2 = (const float*)d_in[3];
  const float* W0 = (const float*)d_in[4];
  const float* b0 = (const float*)d_in[5];
  const float* g0 = (const float*)d_in[6];
  const float* be0 = (const float*)d_in[7];
  const float* W1 = (const float*)d_in[8];
  const float* b1 = (const float*)d_in[9];
  const float* g1 = (const float*)d_in[10];
  const float* be1 = (const float*)d_in[11];
  const float* W2 = (const float*)d_in[12];
  const float* b2 = (const float*)d_in[13];
  const float* g2 = (const float*)d_in[14];
  const float* be2 = (const float*)d_in[15];
  float* out = (float*)d_out;

  char* ws = (char*)d_ws;
  size_t off = 0;
  auto alloc = [&](size_t bytes) -> void* {
    void* p = ws + off;
    off += (bytes + 255) & ~(size_t)255;
    return p;
  };
  int* idx = (int*)alloc((size_t)M_ * 4);
  float4* p1f4 = (float4*)alloc((size_t)B_ * N_ * 16);
  float4* p2f4 = (float4*)alloc((size_t)B_ * N_ * 16);
  float* A = (float*)alloc((size_t)B_ * N_ * 128 * 4);      // 16 MB
  float* Bv = (float*)alloc((size_t)B_ * N_ * 128 * 4);     // 16 MB
  unsigned short* W1b = (unsigned short*)alloc(128 * 128 * 2);
  unsigned short* W2b = (unsigned short*)alloc(128 * 128 * 2);
  float* w0at = (float*)alloc(3 * 128 * 4);
  float* stats = (float*)alloc(3 * 256 * 4);
  float* bnp = (float*)alloc(3 * 256 * 4);
  float* ymaxo = (float*)alloc((size_t)B_ * N_ * 128 * 4);  // 16 MB
  float* ymino = (float*)alloc((size_t)B_ * N_ * 128 * 4);  // 16 MB
  // 128 MB region: KNN scratch during KNN, then x0b (bf16 x0) for the streamed passes.
  char* bigbuf = (char*)alloc((size_t)128 * 1024 * 1024);
  float* pvals = (float*)bigbuf;                                   // 32 MB
  int* cidx = (int*)(bigbuf + (size_t)32 * 1024 * 1024);           // 32 MB
  int* ccnt = (int*)(bigbuf + (size_t)64 * 1024 * 1024);           // 2 MB
  float* Tarr = (float*)(bigbuf + (size_t)66 * 1024 * 1024);       // 128 KB
  unsigned short* x0b = (unsigned short*)bigbuf;                   // 128 MB (after KNN)

  // stats partials aliased onto dead buffers (liveness-checked):
  //  part0 (4 MB, gstats->reduce0) on ymaxo  [ymaxo first written in pass2]
  //  part1 (4 MB, pass1->reduce1)  on ymino  [ymino first written in pass2]
  //  part2 (4 MB, pass2->reduce2)  on A      [A dead after gstats]
  float* part0 = ymaxo;
  float* part1 = ymino;
  float* part2 = A;

  zero_stats<<<3, 256, 0, stream>>>(stats);
  pack_pts<<<B_ * N_ / 256, 256, 0, stream>>>(points1, p1f4);
  pack_pts<<<B_ * N_ / 256, 256, 0, stream>>>(points2, p2f4);
  wcvt<<<64, 256, 0, stream>>>(W1, W1b);
  wcvt<<<64, 256, 0, stream>>>(W2, W2b);
  make_w0at<<<1, 128, 0, stream>>>(W0, w0at);

  knn_part<<<B_ * 64 * CH_, 64, 0, stream>>>(p1f4, p2f4, pvals);
  knn_merge<<<Q_ / 256, 256, 0, stream>>>(pvals, Tarr);
  knn_cand<<<B_ * 64 * CH_, 64, 0, stream>>>(p1f4, p2f4, Tarr, cidx, ccnt);
  knn_combine<<<Q_ / 256, 256, 0, stream>>>(cidx, ccnt, idx);

  pkern<<<B_ * N_ / 32, 256, 0, stream>>>(features1, W0, b0, p1f4, w0at, -1.f, A, 67);
  pkern<<<B_ * N_ / 32, 256, 0, stream>>>(features2, W0, nullptr, p2f4, w0at, 1.f, Bv, 3);

  gstats_kernel<<<NB1_, 256, 0, stream>>>(A, Bv, idx, x0b, part0);
  reduce_atomic<<<NB1_ / 16, 256, 0, stream>>>(part0, stats);
  bnfin_kernel<<<1, 128, 0, stream>>>(stats, g0, be0, bnp);

  pass1_kernel<<<NB1_, 256, 0, stream>>>(x0b, bnp, W1b, b1, part1);
  reduce_atomic<<<NB1_ / 16, 256, 0, stream>>>(part1, stats + 256);
  bnfin_kernel<<<1, 128, 0, stream>>>(stats + 256, g1, be1, bnp + 256);

  pass2_kernel<<<NB1_, 256, 0, stream>>>(x0b, bnp, W1b, b1, bnp + 256,
                                         W2b, b2, ymaxo, ymino, part2);
  reduce_atomic<<<NB1_ / 16, 256, 0, stream>>>(part2, stats + 512);
  bnfin_kernel<<<1, 128, 0, stream>>>(stats + 512, g2, be2, bnp + 512);

  final_kernel<<<B_ * N_ / 64, 256, 0, stream>>>(ymaxo, ymino, bnp + 512, out);
}